// Round 4
// baseline (28.513 us; speedup 1.0000x reference)
//
#include <hip/hip_runtime.h>

typedef int iv4 __attribute__((ext_vector_type(4)));

struct W { double shear, scale, bend; };

__device__ __forceinline__ W softw(const float* __restrict__ rw) {
    double r0 = (double)rw[0], r1 = (double)rw[1], r2 = (double)rw[2];
    double mx = fmax(r0, fmax(r1, r2));
    double e0 = exp(r0 - mx), e1 = exp(r1 - mx), e2 = exp(r2 - mx);
    double s = 1.0 / (e0 + e1 + e2);
    W w; w.shear = e0 * s; w.scale = 0.1 * (e1 * s); w.bend = 0.01 * (e2 * s);
    return w;
}

__device__ __forceinline__ float3 ldv(const float* __restrict__ p) {
    return *reinterpret_cast<const float3*>(p);
}

// Per-face loss*area in double.
__device__ __forceinline__ double face_term(
    float3 s0, float3 s1, float3 s2,
    float3 t0, float3 t1, float3 t2,
    double w_shear, double c_scale, double c_bend)
{
    double e1x = (double)s1.x - s0.x, e1y = (double)s1.y - s0.y, e1z = (double)s1.z - s0.z;
    double e2x = (double)s2.x - s0.x, e2y = (double)s2.y - s0.y, e2z = (double)s2.z - s0.z;
    double f1x = e1x - ((double)t1.x - t0.x), f1y = e1y - ((double)t1.y - t0.y), f1z = e1z - ((double)t1.z - t0.z);
    double f2x = e2x - ((double)t2.x - t0.x), f2y = e2y - ((double)t2.y - t0.y), f2z = e2z - ((double)t2.z - t0.z);

    double a = e1x * e1x + e1y * e1y + e1z * e1z;
    double b = e1x * e2x + e1y * e2y + e1z * e2z;
    double c = e2x * e2x + e2y * e2y + e2z * e2z;
    double det = a * c - b * b;

    double crx = e1y * e2z - e1z * e2y;
    double cry = e1z * e2x - e1x * e2z;
    double crz = e1x * e2y - e1y * e2x;
    double crn = crx * crx + cry * cry + crz * crz;
    double area = 0.5 * sqrt(crn);

    double P = crx * f1x + cry * f1y + crz * f1z;
    double Q = crx * f2x + cry * f2y + crz * f2z;
    double norm_loss = (c * P * P - 2.0 * b * P * Q + a * Q * Q) / (det * crn);

    double fe11 = f1x * e1x + f1y * e1y + f1z * e1z;
    double fe12 = f1x * e2x + f1y * e2y + f1z * e2z;
    double fe21 = f2x * e1x + f2y * e1y + f2z * e1z;
    double fe22 = f2x * e2x + f2y * e2y + f2z * e2z;
    double D00 = 2.0 * fe11;
    double D01 = fe12 + fe21;
    double D11 = 2.0 * fe22;

    double idet = 1.0 / det;
    double inv00 = c * idet, inv01 = -b * idet, inv11 = a * idet;

    double stretch = inv00 * D00 + 2.0 * inv01 * D01 + inv11 * D11;
    double offdiag = inv00 * D01 + inv01 * D11 + inv01 * D00 + inv11 * D01;

    double loss = c_bend * norm_loss + c_scale * stretch + w_shear * offdiag;
    return loss * area;
}

// K1: term[v] for face (v,v+1,v+2). Block stages its 258-row window in LDS
// via coalesced float4 loads (zero redundant global traffic). Also zeroes the
// accumulator/counter used by K2 (stream-ordered, poison-safe).
__global__ void __launch_bounds__(256) term_kernel(
    const float* __restrict__ vs, const float* __restrict__ vt,
    const float* __restrict__ rw, float* __restrict__ term,
    double* __restrict__ acc, unsigned* __restrict__ cnt,
    int nt, int nfl)
{
    __shared__ __align__(16) float ls[776];
    __shared__ __align__(16) float lt[776];
    __shared__ double wsm[3];

    int t = threadIdx.x;
    int vb = blockIdx.x * 256;
    int fbase = vb * 3;

    if (blockIdx.x == 0 && t == 0) { *acc = 0.0; *cnt = 0u; }

    if (t < 194) {                      // 194*4 = 776 floats >= 258 rows * 3
        int fi = fbase + t * 4;
        float4 a, b;
        if (fi + 4 <= nfl) {
            a = *reinterpret_cast<const float4*>(vs + fi);
            b = *reinterpret_cast<const float4*>(vt + fi);
        } else {
            float av[4], bv[4];
            #pragma unroll
            for (int k = 0; k < 4; ++k) {
                int f = fi + k;
                av[k] = (f < nfl) ? vs[f] : 0.0f;
                bv[k] = (f < nfl) ? vt[f] : 0.0f;
            }
            a = make_float4(av[0], av[1], av[2], av[3]);
            b = make_float4(bv[0], bv[1], bv[2], bv[3]);
        }
        *reinterpret_cast<float4*>(ls + t * 4) = a;
        *reinterpret_cast<float4*>(lt + t * 4) = b;
    } else if (t == 255) {              // softmax once per block
        W w = softw(rw);
        wsm[0] = w.shear; wsm[1] = w.scale; wsm[2] = w.bend;
    }
    __syncthreads();

    int v = vb + t;
    if (v >= nt) return;

    const float* s = ls + 3 * t;
    const float* q = lt + 3 * t;
    float3 s0 = make_float3(s[0], s[1], s[2]);
    float3 s1 = make_float3(s[3], s[4], s[5]);
    float3 s2 = make_float3(s[6], s[7], s[8]);
    float3 t0 = make_float3(q[0], q[1], q[2]);
    float3 t1 = make_float3(q[3], q[4], q[5]);
    float3 t2 = make_float3(q[6], q[7], q[8]);
    term[v] = (float)face_term(s0, s1, s2, t0, t1, t2, wsm[0], wsm[1], wsm[2]);
}

__device__ __forceinline__ double quad_sum(iv4 A, iv4 B, iv4 C,
    const float* __restrict__ vs, const float* __restrict__ vt,
    const float* __restrict__ rw, const float* __restrict__ term)
{
    int i0[4] = { A[0], A[3], B[2], C[1] };
    int i1[4] = { A[1], B[0], B[3], C[2] };
    int i2[4] = { A[2], B[1], C[0], C[3] };
    double a = 0.0;
    #pragma unroll
    for (int k = 0; k < 4; ++k) {
        if (__builtin_expect(i1[k] == i0[k] + 1 && i2[k] == i0[k] + 2, 1)) {
            a += (double)term[i0[k]];
        } else {   // never taken for this dataset; correctness insurance
            W w = softw(rw);
            a += face_term(ldv(vs + 3 * i0[k]), ldv(vs + 3 * i1[k]), ldv(vs + 3 * i2[k]),
                           ldv(vt + 3 * i0[k]), ldv(vt + 3 * i1[k]), ldv(vt + 3 * i2[k]),
                           w.shear, w.scale, w.bend);
        }
    }
    return a;
}

// K2: stream faces as coalesced NT int4 (2 strided quads/thread), gather
// term[base], block-reduce, one f64 atomicAdd per block, last block finalizes.
__global__ void __launch_bounds__(256) face_sum(
    const int* __restrict__ face, const float* __restrict__ vs,
    const float* __restrict__ vt, const float* __restrict__ rw,
    const float* __restrict__ term,
    double* __restrict__ acc, unsigned* __restrict__ cnt,
    float* __restrict__ out, int nf, int nblocks, double inv_nf)
{
    int NT = nblocks * 256;
    int t = blockIdx.x * 256 + threadIdx.x;
    int nq = nf >> 2;
    double a = 0.0;

    int q1 = t, q2 = t + NT;
    bool h1 = q1 < nq, h2 = q2 < nq;
    const iv4* p = reinterpret_cast<const iv4*>(face);

    iv4 A1{}, B1{}, C1{}, A2{}, B2{}, C2{};
    if (h1) {
        A1 = __builtin_nontemporal_load(p + 3 * q1 + 0);
        B1 = __builtin_nontemporal_load(p + 3 * q1 + 1);
        C1 = __builtin_nontemporal_load(p + 3 * q1 + 2);
    }
    if (h2) {
        A2 = __builtin_nontemporal_load(p + 3 * q2 + 0);
        B2 = __builtin_nontemporal_load(p + 3 * q2 + 1);
        C2 = __builtin_nontemporal_load(p + 3 * q2 + 2);
    }
    if (h1) a += quad_sum(A1, B1, C1, vs, vt, rw, term);
    if (h2) a += quad_sum(A2, B2, C2, vs, vt, rw, term);

    if (t == 0) {                        // scalar tail (nf % 4 faces; 0 here)
        for (int j = nq * 4; j < nf; ++j) {
            int x = face[3 * j], y = face[3 * j + 1], z = face[3 * j + 2];
            if (y == x + 1 && z == x + 2) {
                a += (double)term[x];
            } else {
                W w = softw(rw);
                a += face_term(ldv(vs + 3 * x), ldv(vs + 3 * y), ldv(vs + 3 * z),
                               ldv(vt + 3 * x), ldv(vt + 3 * y), ldv(vt + 3 * z),
                               w.shear, w.scale, w.bend);
            }
        }
    }

    for (int off = 32; off > 0; off >>= 1)
        a += __shfl_down(a, off);
    __shared__ double sm[4];
    int lane = threadIdx.x & 63;
    int wid = threadIdx.x >> 6;
    if (lane == 0) sm[wid] = a;
    __syncthreads();

    if (threadIdx.x == 0) {
        double bs = sm[0] + sm[1] + sm[2] + sm[3];
        atomicAdd(acc, bs);
        __threadfence();
        unsigned done = atomicAdd(cnt, 1u);
        if (done == (unsigned)(nblocks - 1)) {   // last block out finalizes
            __threadfence();
            double total = atomicAdd(acc, 0.0);  // device-scope read
            out[0] = (float)(total * inv_nf);
        }
    }
}

extern "C" void kernel_launch(void* const* d_in, const int* in_sizes, int n_in,
                              void* d_out, int out_size, void* d_ws, size_t ws_size,
                              hipStream_t stream) {
    const float* vs = (const float*)d_in[0];   // (NV,3) f32
    const float* vt = (const float*)d_in[1];   // (NV,3) f32
    const int* face = (const int*)d_in[2];     // (NF,3) i32
    const float* rw = (const float*)d_in[3];   // (3,) f32
    float* out = (float*)d_out;

    int nv = in_sizes[0] / 3;
    int nf = in_sizes[2] / 3;
    int nt = nv - 3;
    int nfl = nv * 3;

    float* term = (float*)d_ws;
    size_t term_bytes = ((size_t)nt * 4 + 15) & ~(size_t)15;
    double* acc = (double*)((char*)d_ws + term_bytes);
    unsigned* cnt = (unsigned*)((char*)d_ws + term_bytes + 8);

    int blocks1 = (nt + 255) / 256;
    int nq = nf >> 2;
    int blocks2 = ((nq + 1) / 2 + 255) / 256;

    term_kernel<<<blocks1, 256, 0, stream>>>(vs, vt, rw, term, acc, cnt, nt, nfl);
    face_sum<<<blocks2, 256, 0, stream>>>(face, vs, vt, rw, term, acc, cnt,
                                          out, nf, blocks2, 1.0 / (double)nf);
}